// Round 1
// baseline (12282.572 us; speedup 1.0000x reference)
//
#include <hip/hip_runtime.h>

#define U_N 100000
#define I_N 50000
#define N_NODES 150000
#define EMB_D 64
#define NNZ 4800000
#define ND (N_NODES * EMB_D)          /* 9,600,000 floats */
#define ND4 (ND / 4)                  /* 2,400,000 float4 */
#define UD4 (U_N * EMB_D / 4)         /* 1,600,000 float4 */

// emb0 = concat(user, item); acc = emb0
__global__ void k_init_concat(const float4* __restrict__ u,
                              const float4* __restrict__ it,
                              float4* __restrict__ emb0,
                              float4* __restrict__ acc) {
    int i = blockIdx.x * blockDim.x + threadIdx.x;
    if (i >= ND4) return;
    float4 v = (i < UD4) ? u[i] : it[i - UD4];
    emb0[i] = v;
    acc[i]  = v;
}

// push-style SpMM: 16 lanes per edge, one float4 each
__global__ void k_spmm_scatter(const int* __restrict__ row,
                               const int* __restrict__ col,
                               const float* __restrict__ vals,
                               const float* __restrict__ x,
                               float* __restrict__ y) {
    long long t = (long long)blockIdx.x * blockDim.x + threadIdx.x;
    long long e = t >> 4;
    int lane = (int)(t & 15);
    if (e >= NNZ) return;
    int r = row[e];
    int c = col[e];
    float v = vals[e];
    const float4* xr = (const float4*)(x + (long long)c * EMB_D);
    float4 xv = xr[lane];
    float* yr = y + (long long)r * EMB_D + lane * 4;
    unsafeAtomicAdd(yr + 0, v * xv.x);
    unsafeAtomicAdd(yr + 1, v * xv.y);
    unsafeAtomicAdd(yr + 2, v * xv.z);
    unsafeAtomicAdd(yr + 3, v * xv.w);
}

__global__ void k_acc_add(float4* __restrict__ acc, const float4* __restrict__ y) {
    int i = blockIdx.x * blockDim.x + threadIdx.x;
    if (i >= ND4) return;
    float4 a = acc[i], b = y[i];
    a.x += b.x; a.y += b.y; a.z += b.z; a.w += b.w;
    acc[i] = a;
}

// final layer: acc = (acc + y) * 0.25
__global__ void k_acc_add_scale(float4* __restrict__ acc, const float4* __restrict__ y) {
    int i = blockIdx.x * blockDim.x + threadIdx.x;
    if (i >= ND4) return;
    float4 a = acc[i], b = y[i];
    a.x = (a.x + b.x) * 0.25f;
    a.y = (a.y + b.y) * 0.25f;
    a.z = (a.z + b.z) * 0.25f;
    a.w = (a.w + b.w) * 0.25f;
    acc[i] = a;
}

extern "C" void kernel_launch(void* const* d_in, const int* in_sizes, int n_in,
                              void* d_out, int out_size, void* d_ws, size_t ws_size,
                              hipStream_t stream) {
    const float* user_emb = (const float*)d_in[0];
    const float* item_emb = (const float*)d_in[1];
    const int*   row      = (const int*)d_in[2];
    const int*   col      = (const int*)d_in[3];
    const float* vals     = (const float*)d_in[4];

    float* emb0 = (float*)d_out;            // [ND] output 0, also layer-0 x
    float* acc  = (float*)d_out + ND;       // [ND] output 1 accumulator
    float* bufA = (float*)d_ws;             // [ND]
    float* bufB = (float*)d_ws + ND;        // [ND]

    const int BLK = 256;
    const int grid_nd = (ND4 + BLK - 1) / BLK;
    const long long scatter_threads = (long long)NNZ * 16;
    const int grid_sc = (int)((scatter_threads + BLK - 1) / BLK);

    k_init_concat<<<grid_nd, BLK, 0, stream>>>((const float4*)user_emb,
                                               (const float4*)item_emb,
                                               (float4*)emb0, (float4*)acc);

    // layer 1: x = emb0 -> bufA
    hipMemsetAsync(bufA, 0, (size_t)ND * sizeof(float), stream);
    k_spmm_scatter<<<grid_sc, BLK, 0, stream>>>(row, col, vals, emb0, bufA);
    k_acc_add<<<grid_nd, BLK, 0, stream>>>((float4*)acc, (const float4*)bufA);

    // layer 2: bufA -> bufB
    hipMemsetAsync(bufB, 0, (size_t)ND * sizeof(float), stream);
    k_spmm_scatter<<<grid_sc, BLK, 0, stream>>>(row, col, vals, bufA, bufB);
    k_acc_add<<<grid_nd, BLK, 0, stream>>>((float4*)acc, (const float4*)bufB);

    // layer 3: bufB -> bufA, fused final scale
    hipMemsetAsync(bufA, 0, (size_t)ND * sizeof(float), stream);
    k_spmm_scatter<<<grid_sc, BLK, 0, stream>>>(row, col, vals, bufB, bufA);
    k_acc_add_scale<<<grid_nd, BLK, 0, stream>>>((float4*)acc, (const float4*)bufA);
}

// Round 2
// 1208.288 us; speedup vs baseline: 10.1653x; 10.1653x over previous
//
#include <hip/hip_runtime.h>

#define U_N 100000
#define I_N 50000
#define N_NODES 150000
#define EMB_D 64
#define NNZ 4800000
#define ND (N_NODES * EMB_D)          /* 9,600,000 floats */
#define ND4 (ND / 4)                  /* 2,400,000 float4 */
#define UD4 (U_N * EMB_D / 4)         /* 1,600,000 float4 */

#define SCAN_CHUNK 2048               /* elements per scan block (256 thr x 8) */
#define NCHUNK ((N_NODES + SCAN_CHUNK - 1) / SCAN_CHUNK)   /* 74 */

// ---------------- elementwise init: emb0 = concat(u,i); acc = emb0 ----------
__global__ void k_init_concat(const float4* __restrict__ u,
                              const float4* __restrict__ it,
                              float4* __restrict__ emb0,
                              float4* __restrict__ acc) {
    int i = blockIdx.x * blockDim.x + threadIdx.x;
    if (i >= ND4) return;
    float4 v = (i < UD4) ? u[i] : it[i - UD4];
    emb0[i] = v;
    acc[i]  = v;
}

// ---------------- CSR build ----------------
__global__ void k_hist(const int* __restrict__ row, int* __restrict__ deg) {
    int e = blockIdx.x * blockDim.x + threadIdx.x;
    if (e >= NNZ) return;
    atomicAdd(&deg[row[e]], 1);
}

// phase 1: per-chunk exclusive scan of deg -> rp (chunk-local), chunk totals
__global__ void k_scan1(const int* __restrict__ deg, int* __restrict__ rp,
                        int* __restrict__ chunkSums) {
    __shared__ int sdata[256];
    int t = threadIdx.x;
    int base = blockIdx.x * SCAN_CHUNK + t * 8;
    int v[8];
    int s = 0;
#pragma unroll
    for (int j = 0; j < 8; ++j) {
        int idx = base + j;
        v[j] = (idx < N_NODES) ? deg[idx] : 0;
        s += v[j];
    }
    sdata[t] = s;
    __syncthreads();
    // Hillis-Steele inclusive scan over 256 thread sums
    for (int off = 1; off < 256; off <<= 1) {
        int add = 0;
        if (t >= off) add = sdata[t - off];
        __syncthreads();
        sdata[t] += add;
        __syncthreads();
    }
    int run = sdata[t] - s;   // exclusive prefix for this thread within chunk
#pragma unroll
    for (int j = 0; j < 8; ++j) {
        int idx = base + j;
        if (idx < N_NODES) rp[idx] = run;
        run += v[j];
    }
    if (t == 255) chunkSums[blockIdx.x] = sdata[255];
}

// phase 2: serial exclusive scan of the 74 chunk sums (tiny)
__global__ void k_scan2(const int* __restrict__ chunkSums, int* __restrict__ chunkOffs) {
    if (blockIdx.x == 0 && threadIdx.x == 0) {
        int run = 0;
        for (int i = 0; i < NCHUNK; ++i) {
            chunkOffs[i] = run;
            run += chunkSums[i];
        }
    }
}

// phase 3: add chunk offsets; produce final row_ptr and cursor copy
__global__ void k_scan3(int* __restrict__ rp, const int* __restrict__ chunkOffs,
                        int* __restrict__ cursor) {
    int i = blockIdx.x * blockDim.x + threadIdx.x;
    if (i == 0) rp[N_NODES] = NNZ;
    if (i >= N_NODES) return;
    int v = rp[i] + chunkOffs[i / SCAN_CHUNK];
    rp[i] = v;
    cursor[i] = v;
}

// reorder edges into row-sorted (col, val) pairs
__global__ void k_reorder(const int* __restrict__ row, const int* __restrict__ col,
                          const float* __restrict__ vals, int* __restrict__ cursor,
                          int2* __restrict__ edges) {
    int e = blockIdx.x * blockDim.x + threadIdx.x;
    if (e >= NNZ) return;
    int r = row[e];
    int p = atomicAdd(&cursor[r], 1);
    edges[p] = make_int2(col[e], __float_as_int(vals[e]));
}

// ---------------- pull SpMM, one wave per row, lane = dim ----------------
// final_layer==0:  y[row] = s; acc[row] += s
// final_layer==1:  acc[row] = (acc[row] + s) * 0.25   (no y write)
__global__ void k_spmm_pull(const int* __restrict__ rp, const int2* __restrict__ edges,
                            const float* __restrict__ x, float* __restrict__ y,
                            float* __restrict__ acc, int final_layer) {
    int wid = blockIdx.x * (blockDim.x >> 6) + (threadIdx.x >> 6);
    int row = __builtin_amdgcn_readfirstlane(wid);
    if (row >= N_NODES) return;
    int lane = threadIdx.x & 63;

    int start = rp[row];
    int end   = rp[row + 1];

    float s0 = 0.f, s1 = 0.f, s2 = 0.f, s3 = 0.f;
    int e = start;
    for (; e + 4 <= end; e += 4) {
        int2 e0 = edges[e + 0];
        int2 e1 = edges[e + 1];
        int2 e2 = edges[e + 2];
        int2 e3 = edges[e + 3];
        s0 += __int_as_float(e0.y) * x[(size_t)e0.x * EMB_D + lane];
        s1 += __int_as_float(e1.y) * x[(size_t)e1.x * EMB_D + lane];
        s2 += __int_as_float(e2.y) * x[(size_t)e2.x * EMB_D + lane];
        s3 += __int_as_float(e3.y) * x[(size_t)e3.x * EMB_D + lane];
    }
    for (; e < end; ++e) {
        int2 ev = edges[e];
        s0 += __int_as_float(ev.y) * x[(size_t)ev.x * EMB_D + lane];
    }
    float s = (s0 + s1) + (s2 + s3);

    size_t o = (size_t)row * EMB_D + lane;
    if (!final_layer) {
        y[o] = s;
        acc[o] += s;
    } else {
        acc[o] = (acc[o] + s) * 0.25f;
    }
}

extern "C" void kernel_launch(void* const* d_in, const int* in_sizes, int n_in,
                              void* d_out, int out_size, void* d_ws, size_t ws_size,
                              hipStream_t stream) {
    const float* user_emb = (const float*)d_in[0];
    const float* item_emb = (const float*)d_in[1];
    const int*   row      = (const int*)d_in[2];
    const int*   col      = (const int*)d_in[3];
    const float* vals     = (const float*)d_in[4];

    float* emb0 = (float*)d_out;            // [ND] output 0, layer-0 x
    float* acc  = (float*)d_out + ND;       // [ND] output 1 accumulator

    // workspace layout (floats/ints):
    float* bufA = (float*)d_ws;             // [ND]
    float* bufB = (float*)d_ws + ND;        // [ND]
    int2*  edges = (int2*)((float*)d_ws + 2 * (size_t)ND);        // [NNZ] int2
    int*   ibase = (int*)(edges + NNZ);
    int*   deg      = ibase;                            // [N_NODES]
    int*   rp       = ibase + N_NODES;                  // [N_NODES+1]
    int*   cursor   = ibase + 2 * N_NODES + 1;          // [N_NODES]
    int*   chunkSums = ibase + 3 * N_NODES + 1;         // [NCHUNK]
    int*   chunkOffs = chunkSums + NCHUNK;              // [NCHUNK]

    const int BLK = 256;
    const int grid_nd = (ND4 + BLK - 1) / BLK;
    const int grid_e  = (NNZ + BLK - 1) / BLK;
    const int grid_n  = (N_NODES + BLK - 1) / BLK;
    const int grid_spmm = (N_NODES * 64 + BLK - 1) / BLK;  // 4 rows (waves) / block

    // --- init outputs ---
    k_init_concat<<<grid_nd, BLK, 0, stream>>>((const float4*)user_emb,
                                               (const float4*)item_emb,
                                               (float4*)emb0, (float4*)acc);

    // --- CSR build ---
    hipMemsetAsync(deg, 0, (size_t)N_NODES * sizeof(int), stream);
    k_hist<<<grid_e, BLK, 0, stream>>>(row, deg);
    k_scan1<<<NCHUNK, 256, 0, stream>>>(deg, rp, chunkSums);
    k_scan2<<<1, 64, 0, stream>>>(chunkSums, chunkOffs);
    k_scan3<<<grid_n, BLK, 0, stream>>>(rp, chunkOffs, cursor);
    k_reorder<<<grid_e, BLK, 0, stream>>>(row, col, vals, cursor, edges);

    // --- 3 propagation layers (pull, fused acc) ---
    k_spmm_pull<<<grid_spmm, BLK, 0, stream>>>(rp, edges, emb0, bufA, acc, 0);
    k_spmm_pull<<<grid_spmm, BLK, 0, stream>>>(rp, edges, bufA, bufB, acc, 0);
    k_spmm_pull<<<grid_spmm, BLK, 0, stream>>>(rp, edges, bufB, bufA, acc, 1);
}

// Round 3
// 815.500 us; speedup vs baseline: 15.0614x; 1.4817x over previous
//
#include <hip/hip_runtime.h>

#define U_N 100000
#define I_N 50000
#define N_NODES 150000
#define EMB_D 64
#define NNZ 4800000
#define ND (N_NODES * EMB_D)          /* 9,600,000 */
#define ND4 (ND / 4)
#define UD4 (U_N * EMB_D / 4)

#define RPB 1024                              /* rows per bucket */
#define NB ((N_NODES + RPB - 1) / RPB)        /* 147 buckets */
#define TILE 4096                             /* edges per partition tile */
#define NTILE ((NNZ + TILE - 1) / TILE)       /* 1172 */

__device__ __forceinline__ unsigned short f2bf(float f) {
    unsigned int u = __float_as_uint(f);
    unsigned int r = (u + 0x7FFFu + ((u >> 16) & 1u)) >> 16;
    return (unsigned short)r;
}
__device__ __forceinline__ float bf2f(unsigned short h) {
    return __uint_as_float((unsigned int)h << 16);
}

// emb0 = concat(u,i); acc = emb0; hb0 = bf16(emb0)
__global__ void k_init(const float4* __restrict__ u, const float4* __restrict__ it,
                       float4* __restrict__ emb0, float4* __restrict__ acc,
                       ushort4* __restrict__ hb0) {
    int i = blockIdx.x * blockDim.x + threadIdx.x;
    if (i >= ND4) return;
    float4 v = (i < UD4) ? u[i] : it[i - UD4];
    emb0[i] = v;
    acc[i]  = v;
    ushort4 h;
    h.x = f2bf(v.x); h.y = f2bf(v.y); h.z = f2bf(v.z); h.w = f2bf(v.w);
    hb0[i] = h;
}

// ---------------- bucket histogram (LDS-staged) ----------------
__global__ void k_bucket_hist(const int* __restrict__ row, int* __restrict__ bhist) {
    __shared__ int lh[NB];
    int t = threadIdx.x;
    for (int i = t; i < NB; i += 256) lh[i] = 0;
    __syncthreads();
    int base = blockIdx.x * TILE;
    int cnt = min(TILE, NNZ - base);
    for (int i = t; i < cnt; i += 256)
        atomicAdd(&lh[row[base + i] >> 10], 1);
    __syncthreads();
    for (int i = t; i < NB; i += 256)
        if (lh[i]) atomicAdd(&bhist[i], lh[i]);
}

// tiny serial scan of 147 bucket sizes -> bases and append cursors
__global__ void k_bucket_scan(const int* __restrict__ bhist, int* __restrict__ bbase,
                              int* __restrict__ bcur) {
    if (threadIdx.x == 0 && blockIdx.x == 0) {
        int run = 0;
        for (int i = 0; i < NB; ++i) { bbase[i] = run; bcur[i] = run; run += bhist[i]; }
        bbase[NB] = run;
    }
}

// ---------------- phase A: LDS-staged partition into buckets ----------------
// tmp[p] = { (row_local<<18)|col , val_bits } grouped (unordered) by bucket
__global__ void k_partition(const int* __restrict__ row, const int* __restrict__ col,
                            const float* __restrict__ vals, int* __restrict__ bcur,
                            int2* __restrict__ tmp) {
    __shared__ int2 stage[TILE];
    __shared__ unsigned char stageB[TILE];
    __shared__ int hist[NB];
    __shared__ int scn[NB];
    __shared__ int gbase[NB];
    __shared__ int sums[256];
    int t = threadIdx.x;
    for (int i = t; i < NB; i += 256) hist[i] = 0;
    __syncthreads();
    int base = blockIdx.x * TILE;
    int cnt = min(TILE, NNZ - base);

    int  myb[16];
    int  myslot[16];
    int2 myp[16];
#pragma unroll
    for (int j = 0; j < 16; ++j) {
        int i = t + j * 256;
        myb[j] = -1;
        if (i < cnt) {
            int e = base + i;
            int r = row[e];
            int b = r >> 10;
            myb[j] = b;
            myp[j] = make_int2(((r & (RPB - 1)) << 18) | col[e], __float_as_int(vals[e]));
            myslot[j] = atomicAdd(&hist[b], 1);
        }
    }
    __syncthreads();
    // exclusive scan of hist[0..NB) with 256 threads
    int v = (t < NB) ? hist[t] : 0;
    sums[t] = v;
    __syncthreads();
    for (int off = 1; off < 256; off <<= 1) {
        int add = (t >= off) ? sums[t - off] : 0;
        __syncthreads();
        sums[t] += add;
        __syncthreads();
    }
    if (t < NB) scn[t] = sums[t] - v;
    __syncthreads();
    if (t < NB && v > 0) gbase[t] = atomicAdd(&bcur[t], v);
    __syncthreads();
#pragma unroll
    for (int j = 0; j < 16; ++j) {
        if (myb[j] >= 0) {
            int pos = scn[myb[j]] + myslot[j];
            stage[pos] = myp[j];
            stageB[pos] = (unsigned char)myb[j];
        }
    }
    __syncthreads();
    // stream out: contiguous runs per bucket -> coalesced full-line writes
    for (int i = t; i < cnt; i += 256) {
        int b = stageB[i];
        tmp[gbase[b] + (i - scn[b])] = stage[i];
    }
}

// ---------------- phase B: per-bucket exact CSR (one WG per bucket) ---------
__global__ void k_bucket_csr(const int* __restrict__ bbase, const int2* __restrict__ tmp,
                             int2* __restrict__ edges, int* __restrict__ rp) {
    __shared__ int lh[RPB];
    __shared__ int lsc[RPB];
    __shared__ int sums[256];
    int b = blockIdx.x, t = threadIdx.x;
    int s0 = bbase[b], s1 = bbase[b + 1];
    int n = s1 - s0;
    for (int i = t; i < RPB; i += 256) lh[i] = 0;
    __syncthreads();
    for (int i = t; i < n; i += 256)
        atomicAdd(&lh[(unsigned)tmp[s0 + i].x >> 18], 1);
    __syncthreads();
    // scan 1024 entries: thread t owns [4t, 4t+4)
    int a0 = lh[t * 4], a1 = lh[t * 4 + 1], a2 = lh[t * 4 + 2], a3 = lh[t * 4 + 3];
    int s = a0 + a1 + a2 + a3;
    sums[t] = s;
    __syncthreads();
    for (int off = 1; off < 256; off <<= 1) {
        int add = (t >= off) ? sums[t - off] : 0;
        __syncthreads();
        sums[t] += add;
        __syncthreads();
    }
    int run = sums[t] - s;
    lsc[t * 4] = run; run += a0;
    lsc[t * 4 + 1] = run; run += a1;
    lsc[t * 4 + 2] = run; run += a2;
    lsc[t * 4 + 3] = run;
    __syncthreads();
    for (int rl = t; rl < RPB; rl += 256) {
        int r = b * RPB + rl;
        if (r < N_NODES) rp[r] = s0 + lsc[rl];
    }
    if (b == NB - 1 && t == 0) rp[N_NODES] = NNZ;
    // reuse lh as per-row cursor
    for (int i = t; i < RPB; i += 256) lh[i] = lsc[i];
    __syncthreads();
    // scatter within an L2-resident ~260 KB region (single WG = single XCD)
    for (int i = t; i < n; i += 256) {
        int2 p = tmp[s0 + i];
        int rl = (unsigned)p.x >> 18;
        int pos = s0 + atomicAdd(&lh[rl], 1);
        edges[pos] = make_int2(p.x & 0x3FFFF, p.y);
    }
}

// ---------------- pull SpMM, one wave per row, lane = dim, bf16 gather ------
// FINAL=0: y[row]=bf16(s); acc+=s.  FINAL=1: acc=(acc+s)*0.25
template <int FINAL>
__global__ void k_spmm(const int* __restrict__ rp, const int2* __restrict__ edges,
                       const unsigned short* __restrict__ x,
                       unsigned short* __restrict__ y, float* __restrict__ acc) {
    int wid = blockIdx.x * (blockDim.x >> 6) + (threadIdx.x >> 6);
    if (wid >= N_NODES) return;
    int lane = threadIdx.x & 63;
    int start = rp[wid];
    int end   = rp[wid + 1];

    float s0 = 0.f, s1 = 0.f, s2 = 0.f, s3 = 0.f;
    int e = start;
    for (; e + 4 <= end; e += 4) {
        int2 e0 = edges[e + 0];
        int2 e1 = edges[e + 1];
        int2 e2 = edges[e + 2];
        int2 e3 = edges[e + 3];
        s0 += __int_as_float(e0.y) * bf2f(x[(size_t)e0.x * EMB_D + lane]);
        s1 += __int_as_float(e1.y) * bf2f(x[(size_t)e1.x * EMB_D + lane]);
        s2 += __int_as_float(e2.y) * bf2f(x[(size_t)e2.x * EMB_D + lane]);
        s3 += __int_as_float(e3.y) * bf2f(x[(size_t)e3.x * EMB_D + lane]);
    }
    for (; e < end; ++e) {
        int2 ev = edges[e];
        s0 += __int_as_float(ev.y) * bf2f(x[(size_t)ev.x * EMB_D + lane]);
    }
    float s = (s0 + s1) + (s2 + s3);

    size_t o = (size_t)wid * EMB_D + lane;
    if (FINAL) {
        acc[o] = (acc[o] + s) * 0.25f;
    } else {
        y[o] = f2bf(s);
        acc[o] += s;
    }
}

extern "C" void kernel_launch(void* const* d_in, const int* in_sizes, int n_in,
                              void* d_out, int out_size, void* d_ws, size_t ws_size,
                              hipStream_t stream) {
    const float* user_emb = (const float*)d_in[0];
    const float* item_emb = (const float*)d_in[1];
    const int*   row      = (const int*)d_in[2];
    const int*   col      = (const int*)d_in[3];
    const float* vals     = (const float*)d_in[4];

    float* emb0 = (float*)d_out;            // [ND] output 0
    float* acc  = (float*)d_out + ND;       // [ND] output 1

    // ws layout: [tmp int2[NNZ] | edges int2[NNZ] | rp, bhist, bbase, bcur]
    // tmp region (38.4 MB) is dead after k_bucket_csr -> reused as hb0/hb1 bf16
    int2* tmp   = (int2*)d_ws;
    int2* edges = tmp + NNZ;
    int*  ibase = (int*)(edges + NNZ);
    int*  rp    = ibase;                     // [N_NODES+1]
    int*  bhist = ibase + N_NODES + 1;       // [NB]
    int*  bbase = bhist + NB;                // [NB+1]
    int*  bcur  = bbase + NB + 1;            // [NB]
    unsigned short* hb0 = (unsigned short*)d_ws;        // [ND] aliases tmp
    unsigned short* hb1 = hb0 + ND;                     // [ND]

    const int BLK = 256;
    const int grid_nd = (ND4 + BLK - 1) / BLK;
    const int grid_spmm = (N_NODES * 64 + BLK - 1) / BLK;  // 1 wave per row

    // --- CSR build: hist -> scan -> partition -> per-bucket sort ---
    hipMemsetAsync(bhist, 0, NB * sizeof(int), stream);
    k_bucket_hist<<<NTILE, BLK, 0, stream>>>(row, bhist);
    k_bucket_scan<<<1, 64, 0, stream>>>(bhist, bbase, bcur);
    k_partition<<<NTILE, BLK, 0, stream>>>(row, col, vals, bcur, tmp);
    k_bucket_csr<<<NB, BLK, 0, stream>>>(bbase, tmp, edges, rp);

    // --- init outputs + bf16 layer-0 (overwrites tmp region) ---
    k_init<<<grid_nd, BLK, 0, stream>>>((const float4*)user_emb,
                                        (const float4*)item_emb,
                                        (float4*)emb0, (float4*)acc,
                                        (ushort4*)hb0);

    // --- 3 propagation layers ---
    k_spmm<0><<<grid_spmm, BLK, 0, stream>>>(rp, edges, hb0, hb1, acc);
    k_spmm<0><<<grid_spmm, BLK, 0, stream>>>(rp, edges, hb1, hb0, acc);
    k_spmm<1><<<grid_spmm, BLK, 0, stream>>>(rp, edges, hb0, (unsigned short*)nullptr, acc);
}

// Round 4
// 625.710 us; speedup vs baseline: 19.6298x; 1.3033x over previous
//
#include <hip/hip_runtime.h>

#define U_N 100000
#define I_N 50000
#define N_NODES 150000
#define EMB_D 64
#define NNZ 4800000
#define ND (N_NODES * EMB_D)          /* 9,600,000 */
#define ND4 (ND / 4)
#define UD4 (U_N * EMB_D / 4)

#define RPB 1024                              /* rows per bucket */
#define NB ((N_NODES + RPB - 1) / RPB)        /* 147 buckets */
#define TILE 4096                             /* edges per partition tile */
#define NTILE ((NNZ + TILE - 1) / TILE)       /* 1172 */

__device__ __forceinline__ unsigned short f2bf(float f) {
    unsigned int u = __float_as_uint(f);
    unsigned int r = (u + 0x7FFFu + ((u >> 16) & 1u)) >> 16;
    return (unsigned short)r;
}
__device__ __forceinline__ float bf2f(unsigned short h) {
    return __uint_as_float((unsigned int)h << 16);
}

// emb0 = concat(u,i); hb0 = bf16(emb0)   (acc write deferred to final layer)
__global__ void k_init(const float4* __restrict__ u, const float4* __restrict__ it,
                       float4* __restrict__ emb0, ushort4* __restrict__ hb0) {
    int i = blockIdx.x * blockDim.x + threadIdx.x;
    if (i >= ND4) return;
    float4 v = (i < UD4) ? u[i] : it[i - UD4];
    emb0[i] = v;
    ushort4 h;
    h.x = f2bf(v.x); h.y = f2bf(v.y); h.z = f2bf(v.z); h.w = f2bf(v.w);
    hb0[i] = h;
}

// ---------------- bucket histogram (LDS-staged) ----------------
__global__ void k_bucket_hist(const int* __restrict__ row, int* __restrict__ bhist) {
    __shared__ int lh[NB];
    int t = threadIdx.x;
    for (int i = t; i < NB; i += 256) lh[i] = 0;
    __syncthreads();
    int base = blockIdx.x * TILE;
    int cnt = min(TILE, NNZ - base);
    for (int i = t; i < cnt; i += 256)
        atomicAdd(&lh[row[base + i] >> 10], 1);
    __syncthreads();
    for (int i = t; i < NB; i += 256)
        if (lh[i]) atomicAdd(&bhist[i], lh[i]);
}

__global__ void k_bucket_scan(const int* __restrict__ bhist, int* __restrict__ bbase,
                              int* __restrict__ bcur) {
    if (threadIdx.x == 0 && blockIdx.x == 0) {
        int run = 0;
        for (int i = 0; i < NB; ++i) { bbase[i] = run; bcur[i] = run; run += bhist[i]; }
        bbase[NB] = run;
    }
}

// ---------------- phase A: LDS-staged partition into buckets ----------------
// tmp[p] = { (row_local<<18)|col , val_bits } grouped (unordered) by bucket
__global__ void k_partition(const int* __restrict__ row, const int* __restrict__ col,
                            const float* __restrict__ vals, int* __restrict__ bcur,
                            int2* __restrict__ tmp) {
    __shared__ int2 stage[TILE];
    __shared__ unsigned char stageB[TILE];
    __shared__ int hist[NB];
    __shared__ int scn[NB];
    __shared__ int gbase[NB];
    __shared__ int sums[256];
    int t = threadIdx.x;
    for (int i = t; i < NB; i += 256) hist[i] = 0;
    __syncthreads();
    int base = blockIdx.x * TILE;
    int cnt = min(TILE, NNZ - base);

    int  myb[16];
    int  myslot[16];
    int2 myp[16];
#pragma unroll
    for (int j = 0; j < 16; ++j) {
        int i = t + j * 256;
        myb[j] = -1;
        if (i < cnt) {
            int e = base + i;
            int r = row[e];
            int b = r >> 10;
            myb[j] = b;
            myp[j] = make_int2(((r & (RPB - 1)) << 18) | col[e], __float_as_int(vals[e]));
            myslot[j] = atomicAdd(&hist[b], 1);
        }
    }
    __syncthreads();
    int v = (t < NB) ? hist[t] : 0;
    sums[t] = v;
    __syncthreads();
    for (int off = 1; off < 256; off <<= 1) {
        int add = (t >= off) ? sums[t - off] : 0;
        __syncthreads();
        sums[t] += add;
        __syncthreads();
    }
    if (t < NB) scn[t] = sums[t] - v;
    __syncthreads();
    if (t < NB && v > 0) gbase[t] = atomicAdd(&bcur[t], v);
    __syncthreads();
#pragma unroll
    for (int j = 0; j < 16; ++j) {
        if (myb[j] >= 0) {
            int pos = scn[myb[j]] + myslot[j];
            stage[pos] = myp[j];
            stageB[pos] = (unsigned char)myb[j];
        }
    }
    __syncthreads();
    for (int i = t; i < cnt; i += 256) {
        int b = stageB[i];
        tmp[gbase[b] + (i - scn[b])] = stage[i];
    }
}

// ---------------- phase B: per-bucket exact CSR, 1024 thr (1/row) ----------
__global__ void k_bucket_csr(const int* __restrict__ bbase, const int2* __restrict__ tmp,
                             int2* __restrict__ edges, int* __restrict__ rp) {
    __shared__ int lh[RPB];
    __shared__ int lsc[RPB];
    int b = blockIdx.x, t = threadIdx.x;           // 1024 threads
    int s0 = bbase[b], s1 = bbase[b + 1];
    int n = s1 - s0;
    lh[t] = 0;
    __syncthreads();
    for (int i = t; i < n; i += 1024)
        atomicAdd(&lh[(unsigned)tmp[s0 + i].x >> 18], 1);
    __syncthreads();
    int v = lh[t];
    lsc[t] = v;
    __syncthreads();
    for (int off = 1; off < 1024; off <<= 1) {
        int add = (t >= off) ? lsc[t - off] : 0;
        __syncthreads();
        lsc[t] += add;
        __syncthreads();
    }
    int excl = lsc[t] - v;                          // exclusive prefix
    int r = b * RPB + t;
    if (r < N_NODES) rp[r] = s0 + excl;
    if (b == NB - 1 && t == 0) rp[N_NODES] = NNZ;
    __syncthreads();
    lh[t] = excl;                                   // per-row cursor
    __syncthreads();
    for (int i = t; i < n; i += 1024) {
        int2 p = tmp[s0 + i];
        int rl = (unsigned)p.x >> 18;
        int pos = s0 + atomicAdd(&lh[rl], 1);
        edges[pos] = make_int2(p.x & 0x3FFFF, p.y);
    }
}

// ---------------- pull SpMM, one wave per row, lane = dim, bf16 gather ------
__device__ __forceinline__ float row_dot(const int* __restrict__ rp,
                                         const int2* __restrict__ edges,
                                         const unsigned short* __restrict__ x,
                                         int wid, int lane) {
    int start = __builtin_amdgcn_readfirstlane(rp[wid]);
    int end   = __builtin_amdgcn_readfirstlane(rp[wid + 1]);
    float s0 = 0.f, s1 = 0.f, s2 = 0.f, s3 = 0.f;
    int e = start;
    for (; e + 8 <= end; e += 8) {
        int2 E[8];
#pragma unroll
        for (int j = 0; j < 8; ++j) E[j] = edges[e + j];
        float g[8];
#pragma unroll
        for (int j = 0; j < 8; ++j) g[j] = bf2f(x[(size_t)E[j].x * EMB_D + lane]);
        s0 += __int_as_float(E[0].y) * g[0];
        s1 += __int_as_float(E[1].y) * g[1];
        s2 += __int_as_float(E[2].y) * g[2];
        s3 += __int_as_float(E[3].y) * g[3];
        s0 += __int_as_float(E[4].y) * g[4];
        s1 += __int_as_float(E[5].y) * g[5];
        s2 += __int_as_float(E[6].y) * g[6];
        s3 += __int_as_float(E[7].y) * g[7];
    }
    for (; e < end; ++e) {
        int2 ev = edges[e];
        s0 += __int_as_float(ev.y) * bf2f(x[(size_t)ev.x * EMB_D + lane]);
    }
    return (s0 + s1) + (s2 + s3);
}

// layers 1,2: y = bf16(spmm(x)) only
__global__ void k_spmm_mid(const int* __restrict__ rp, const int2* __restrict__ edges,
                           const unsigned short* __restrict__ x,
                           unsigned short* __restrict__ y) {
    int wid = blockIdx.x * (blockDim.x >> 6) + (threadIdx.x >> 6);
    if (wid >= N_NODES) return;
    int lane = threadIdx.x & 63;
    float s = row_dot(rp, edges, x, wid, lane);
    y[(size_t)wid * EMB_D + lane] = f2bf(s);
}

// layer 3: acc = (emb0 + y1 + y2 + s) * 0.25
__global__ void k_spmm_fin(const int* __restrict__ rp, const int2* __restrict__ edges,
                           const unsigned short* __restrict__ x,
                           const float* __restrict__ emb0,
                           const unsigned short* __restrict__ y1,
                           const unsigned short* __restrict__ y2,
                           float* __restrict__ acc) {
    int wid = blockIdx.x * (blockDim.x >> 6) + (threadIdx.x >> 6);
    if (wid >= N_NODES) return;
    int lane = threadIdx.x & 63;
    float s = row_dot(rp, edges, x, wid, lane);
    size_t o = (size_t)wid * EMB_D + lane;
    acc[o] = (emb0[o] + bf2f(y1[o]) + bf2f(y2[o]) + s) * 0.25f;
}

extern "C" void kernel_launch(void* const* d_in, const int* in_sizes, int n_in,
                              void* d_out, int out_size, void* d_ws, size_t ws_size,
                              hipStream_t stream) {
    const float* user_emb = (const float*)d_in[0];
    const float* item_emb = (const float*)d_in[1];
    const int*   row      = (const int*)d_in[2];
    const int*   col      = (const int*)d_in[3];
    const float* vals     = (const float*)d_in[4];

    float* emb0 = (float*)d_out;            // [ND] output 0
    float* acc  = (float*)d_out + ND;       // [ND] output 1

    // ws: [tmp int2[NNZ] | edges int2[NNZ] | hb2 ushort[ND] | ints]
    // tmp (38.4 MB) is dead after k_bucket_csr -> reused as hb0/hb1 bf16
    int2* tmp   = (int2*)d_ws;
    int2* edges = tmp + NNZ;
    unsigned short* hb2 = (unsigned short*)(edges + NNZ);   // [ND]
    int*  ibase = (int*)(hb2 + ND);
    int*  rp    = ibase;                     // [N_NODES+1]
    int*  bhist = ibase + N_NODES + 1;       // [NB]
    int*  bbase = bhist + NB;                // [NB+1]
    int*  bcur  = bbase + NB + 1;            // [NB]
    unsigned short* hb0 = (unsigned short*)d_ws;   // [ND] aliases tmp
    unsigned short* hb1 = hb0 + ND;                // [ND]

    const int BLK = 256;
    const int grid_nd = (ND4 + BLK - 1) / BLK;
    const int grid_spmm = (N_NODES * 64 + BLK - 1) / BLK;  // 1 wave per row

    // --- CSR build: hist -> scan -> partition -> per-bucket sort ---
    hipMemsetAsync(bhist, 0, NB * sizeof(int), stream);
    k_bucket_hist<<<NTILE, BLK, 0, stream>>>(row, bhist);
    k_bucket_scan<<<1, 64, 0, stream>>>(bhist, bbase, bcur);
    k_partition<<<NTILE, BLK, 0, stream>>>(row, col, vals, bcur, tmp);
    k_bucket_csr<<<NB, 1024, 0, stream>>>(bbase, tmp, edges, rp);

    // --- init outputs + bf16 layer-0 (overwrites tmp region) ---
    k_init<<<grid_nd, BLK, 0, stream>>>((const float4*)user_emb,
                                        (const float4*)item_emb,
                                        (float4*)emb0, (ushort4*)hb0);

    // --- 3 propagation layers, acc deferred to the final pass ---
    k_spmm_mid<<<grid_spmm, BLK, 0, stream>>>(rp, edges, hb0, hb1);
    k_spmm_mid<<<grid_spmm, BLK, 0, stream>>>(rp, edges, hb1, hb2);
    k_spmm_fin<<<grid_spmm, BLK, 0, stream>>>(rp, edges, hb2, emb0, hb1, hb2, acc);
}